// Round 12
// baseline (609.946 us; speedup 1.0000x reference)
//
#include <hip/hip_runtime.h>
#include <hip/hip_bf16.h>
#include <stdint.h>

#define D_MODEL 1024
#define NH 16
#define DK 64
#define S_LEN 2048
#define GRID_N 768u

typedef __attribute__((ext_vector_type(8))) __bf16 bf16x8;
typedef __attribute__((ext_vector_type(4))) float f32x4;

#define GLOBAL_AS __attribute__((address_space(1)))
#define LDS_AS    __attribute__((address_space(3)))

// async global->LDS DMA, 16B per lane; lane i's 16B lands at ldsbase + i*16.
__device__ __forceinline__ void async16(const ushort* g, ushort* l) {
    __builtin_amdgcn_global_load_lds(
        (const GLOBAL_AS uint32_t*)(uintptr_t)(const void*)g,
        (LDS_AS uint32_t*)(uint32_t)(uintptr_t)(void*)l,
        16, 0, 0);
}

// raw barrier with fine-grained vmcnt: waits until <=N VMEM ops outstanding.
template <int N>
__device__ __forceinline__ void pipe_barrier() {
    asm volatile("s_waitcnt vmcnt(%0)\n\ts_barrier" :: "n"(N) : "memory");
}

__device__ __forceinline__ float fast_exp2(float x) {
    float r;
    asm("v_exp_f32 %0, %1" : "=v"(r) : "v"(x));   // D = 2^S0
    return r;
}

// fp32 -> bf16 (RNE)
__device__ __forceinline__ ushort f2bf(float f) {
    union { float f; uint32_t u; } v; v.f = f;
    uint32_t lsb = (v.u >> 16) & 1u;
    return (ushort)((v.u + 0x7fffu + lsb) >> 16);
}

// two fp32 -> packed bf16x2 (round-half-up)
__device__ __forceinline__ uint32_t packbf(float a, float b) {
    union { float f; uint32_t u; } x, y; x.f = a; y.f = b;
    return ((x.u + 0x8000u) >> 16) | ((y.u + 0x8000u) & 0xffff0000u);
}

// two fp32 -> packed bf16x2 via native v_cvt_pk_bf16_f32 (RNE, 1 instr)
__device__ __forceinline__ uint32_t packbf_rn(float a, float b) {
    union { __hip_bfloat162 h; uint32_t u; } cv;
    cv.h = __float22bfloat162_rn(make_float2(a, b));
    return cv.u;
}

__device__ __forceinline__ bf16x8 ldfrag(const ushort* p) {
    union { uint4 u; bf16x8 b; } cv;
    cv.u = *(const uint4*)p;
    return cv.b;
}

// software grid barrier: ticketed spin on a device-scope counter.
// Counter is hipMemsetAsync'd to 0 before launch (replayed per graph rep).
// Barrier b releases at count (b+1)*GRID_N; one counter serves all barriers.
// Deadlock-free by construction: lb(256,3) + 48KB LDS -> 3 blocks/CU ->
// all 768 blocks co-resident.
__device__ __forceinline__ void grid_bar(uint32_t* cnt) {
    __syncthreads();
    if (threadIdx.x == 0) {
        __threadfence();                 // release my writes (device scope)
        uint32_t ticket = __hip_atomic_fetch_add(
            cnt, 1u, __ATOMIC_ACQ_REL, __HIP_MEMORY_SCOPE_AGENT);
        uint32_t target = (ticket / GRID_N + 1u) * GRID_N;
        while (__hip_atomic_load(cnt, __ATOMIC_ACQUIRE,
                                 __HIP_MEMORY_SCOPE_AGENT) < target)
            __builtin_amdgcn_s_sleep(16);
        __threadfence();                 // acquire: invalidate this CU's L1
    }
    __syncthreads();
}

// ---------------- MFMA GEMM body ----------------------------------------------
// BK=32, THREE buffers (48/36 KB). Stage issued at loop top; awaited stage is
// ~1 iteration old. Full unroll makes the %3 buffer rotation static.
// MODE 0: tile 128x128, 768 tiles, N-striped XCD. Block wholly Q, K or V.
// MODE 1: tile 128x64, 512 tiles, M-striped XCD; out = acc + bias + residual.
template <int MODE>
__device__ __forceinline__ void gemm_body(
    int bid, ushort* smem,
    const ushort* __restrict__ A, const ushort* __restrict__ Bt,
    const float* __restrict__ bias,
    ushort* __restrict__ outQ, ushort* __restrict__ outK, ushort* __restrict__ outVt,
    const float* __restrict__ xres, float* __restrict__ outF) {
    constexpr int BN = (MODE == 0) ? 128 : 64;
    constexpr int NI = (MODE == 0) ? 4 : 2;
    constexpr int NS = (MODE == 0) ? 4 : 3;        // per-wave DMA instrs / stage
    constexpr int ABUF = 4096;                     // ushorts per A buffer
    constexpr int BBUF = (MODE == 0) ? 4096 : 2048;
    ushort* sAb = smem;
    ushort* sBb = smem + 3 * ABUF;

    const int tid = threadIdx.x;
    const int wave = tid >> 6, lane = tid & 63;
    const int lr = lane & 15, lq = lane >> 4;
    const int srow = lane >> 3, sp = lane & 7;     // staging: 8 lanes / 128B row

    const int xcd = bid & 7, lb = bid >> 3;
    int bx, by;
    if (MODE == 0) { bx = xcd * 3 + (lb % 3); by = lb / 3; }       // N-stripe
    else           { by = xcd * 4 + (lb & 3); bx = lb >> 2; }      // M-stripe
    const int blockM = by * 128;
    const int blockN = bx * BN;
    const int waveM = (wave >> 1) * 64;
    const int waveN = (MODE == 0) ? (wave & 1) * 64 : (wave & 1) * 32;

    // stage one BK=32 tile pair into buffer `buf`
    auto stage = [&](int k0, int buf) {
        ushort* a = sAb + buf * ABUF;
#pragma unroll
        for (int t = 0; t < 2; t++) {
            int Rb = wave * 16 + t * 8;            // uniform LDS row base
            int R = Rb + srow;
            int L = sp ^ (R & 7);
            int m = 2 * R + (L >> 2);
            int kc = L & 3;
            async16(&A[(size_t)(blockM + m) * D_MODEL + k0 + kc * 8], a + Rb * 64);
        }
        ushort* b = sBb + buf * BBUF;
        if (MODE == 0) {
#pragma unroll
            for (int t = 0; t < 2; t++) {
                int Rb = wave * 16 + t * 8;
                int R = Rb + srow;
                int L = sp ^ (R & 7);
                int n = 2 * R + (L >> 2);
                int kc = L & 3;
                async16(&Bt[(size_t)(blockN + n) * D_MODEL + k0 + kc * 8], b + Rb * 64);
            }
        } else {
            int Rb = wave * 8;
            int R = Rb + srow;
            int L = sp ^ (R & 7);
            int n = 2 * R + (L >> 2);
            int kc = L & 3;
            async16(&Bt[(size_t)(blockN + n) * D_MODEL + k0 + kc * 8], b + Rb * 64);
        }
    };

    // fragment read offsets (row-xor invariant across mi since rows step by 8)
    const int RA = (waveM >> 1) + (lr >> 1);
    const int offA = RA * 64 + ((((lr & 1) * 4 + lq) ^ (RA & 7)) * 8);
    const int RB = (waveN >> 1) + (lr >> 1);
    const int offB = RB * 64 + ((((lr & 1) * 4 + lq) ^ (RB & 7)) * 8);

    f32x4 acc[4][NI] = {};

    stage(0, 0);
    stage(32, 1);
    pipe_barrier<NS>();   // buf0 landed; buf1 in flight

#pragma unroll
    for (int k = 0; k < 32; k++) {
        const int buf = k % 3;
        if (k + 2 < 32) stage((k + 2) * 32, (k + 2) % 3);
        const ushort* a = sAb + buf * ABUF;
        const ushort* b = sBb + buf * BBUF;
        bf16x8 af[4], bfr[NI];
#pragma unroll
        for (int mi = 0; mi < 4; mi++)
            af[mi] = ldfrag(&a[offA + mi * 512]);
#pragma unroll
        for (int ni = 0; ni < NI; ni++)
            bfr[ni] = ldfrag(&b[offB + ni * 512]);
#pragma unroll
        for (int mi = 0; mi < 4; mi++)
#pragma unroll
            for (int ni = 0; ni < NI; ni++)
                acc[mi][ni] = __builtin_amdgcn_mfma_f32_16x16x32_bf16(
                    af[mi], bfr[ni], acc[mi][ni], 0, 0, 0);
        if (k < 30) pipe_barrier<NS>();           // awaited stage is ~1 iter old
        else if (k == 30) pipe_barrier<0>();
    }
    __syncthreads();   // all K-loop LDS reads done; smem reused for epilogue

    const int bglob = blockM >> 11;
    const int sbase = blockM & 2047;

    if (MODE == 0) {
        const int which = bx >> 3;                // 0=Q 1=K 2=V, uniform per block
        if (which < 2) {
            // C -> LDS [m][n], stride 136, then coalesced [bh][s][d] stores
            const float scale = (which == 0) ? 0.1803368801f : 1.0f;  // 1/8*log2e
#pragma unroll
            for (int ni = 0; ni < 4; ni++) {
                const int n_loc = waveN + ni * 16 + lr;
                const float bn = bias[blockN + n_loc];
#pragma unroll
                for (int mi = 0; mi < 4; mi++)
#pragma unroll
                    for (int r = 0; r < 4; r++) {
                        int m_loc = waveM + mi * 16 + lq * 4 + r;
                        smem[m_loc * 136 + n_loc] =
                            f2bf((acc[mi][ni][r] + bn) * scale);
                    }
            }
            __syncthreads();
            ushort* outp = (which == 0) ? outQ : outK;
            const int hbase = (which == 0) ? bx * 2 : (bx - 8) * 2;
#pragma unroll
            for (int j = 0; j < 8; j++) {
                int c = tid + j * 256;            // 2048 chunks of 16B
                int m = c >> 4, nc = c & 15;
                int hh = nc >> 3, d8 = nc & 7;
                uint4 w = *(uint4*)&smem[m * 136 + nc * 8];
                size_t bh = (size_t)(bglob * NH + hbase + hh);
                *(uint4*)&outp[(bh * S_LEN + sbase + m) * DK + d8 * 8] = w;
            }
        } else {
            // V: C -> LDS [n][m] (b64 packed writes), then [bh][d][s] stores
#pragma unroll
            for (int ni = 0; ni < 4; ni++) {
                const int n_loc = waveN + ni * 16 + lr;
                const float bn = bias[blockN + n_loc];
#pragma unroll
                for (int mi = 0; mi < 4; mi++) {
                    uint2 w;
                    w.x = packbf(acc[mi][ni][0] + bn, acc[mi][ni][1] + bn);
                    w.y = packbf(acc[mi][ni][2] + bn, acc[mi][ni][3] + bn);
                    int m_base = waveM + mi * 16 + lq * 4;
                    *(uint2*)&smem[n_loc * 136 + m_base] = w;
                }
            }
            __syncthreads();
            const int hbase = (bx - 16) * 2;
#pragma unroll
            for (int j = 0; j < 8; j++) {
                int c = tid + j * 256;
                int n_loc = c >> 4, m8 = c & 15;
                int d = n_loc & 63, hh = n_loc >> 6;
                uint4 w = *(uint4*)&smem[n_loc * 136 + m8 * 8];
                size_t bh = (size_t)(bglob * NH + hbase + hh);
                *(uint4*)&outVt[(bh * DK + d) * S_LEN + sbase + m8 * 8] = w;
            }
        }
    } else {
        // fp32 out: C+bias -> LDS [m][n] stride 68, then +residual float4 stores
        float* sCf = (float*)smem;
#pragma unroll
        for (int ni = 0; ni < 2; ni++) {
            const int n_loc = waveN + ni * 16 + lr;
            const float bn = bias[blockN + n_loc];
#pragma unroll
            for (int mi = 0; mi < 4; mi++)
#pragma unroll
                for (int r = 0; r < 4; r++) {
                    int m_loc = waveM + mi * 16 + lq * 4 + r;
                    sCf[m_loc * 68 + n_loc] = acc[mi][ni][r] + bn;
                }
        }
        __syncthreads();
#pragma unroll
        for (int j = 0; j < 8; j++) {
            int c = tid + j * 256;               // 2048 chunks of 16B
            int m = c >> 4, nc = c & 15;
            float4 v = *(float4*)&sCf[m * 68 + nc * 4];
            size_t idx = (size_t)(blockM + m) * D_MODEL + blockN + nc * 4;
            float4 xr = *(const float4*)&xres[idx];
            v.x += xr.x; v.y += xr.y; v.z += xr.z; v.w += xr.w;
            *(float4*)&outF[idx] = v;
        }
    }
}

// ---------------- flash attention body ----------------------------------------
// R5 2-buffer variant (best measured, 46.1us, 48KB LDS): K prefetch dist 2
// into kb[k&1], V dist 1 into vb[(k+1)&1]; per-iter vmcnt(0)+barrier fences
// the buffer reuse. 4 waves x 32 q-rows, pipelined schedule:
// stage -> QK(k+1) -> PV(k) -> barrier -> exp(k+1).
__device__ __forceinline__ void attn_body(
    int bid, ushort* smem,
    const ushort* __restrict__ Q, const ushort* __restrict__ Km,
    const ushort* __restrict__ Vt, ushort* __restrict__ ctx) {
    const int xcd = bid & 7, lb = bid >> 3;
    const int bh = xcd * 4 + (lb & 3);
    const int qt = lb >> 2;
    const int q0 = qt * 128;
    ushort* sKb = smem;                  // [2][64*64]  16 KB
    ushort* sVb = smem + 8192;           // [2][64*64]  16 KB
    ushort* sQP = smem + 16384;          // [4][32*64]  16 KB
    const int tid = threadIdx.x;
    const int wave = tid >> 6, lane = tid & 63;
    const int lr = lane & 15, lq = lane >> 4;
    const int srow = lane >> 3, sp = lane & 7;
    const ushort* Qh = Q + (size_t)bh * S_LEN * DK;
    const ushort* Kh = Km + (size_t)bh * S_LEN * DK;
    const ushort* Vh = Vt + (size_t)bh * DK * S_LEN;
    ushort* sPw = sQP + wave * 2048;

    // stage this wave's 32 Q rows (swizzled chunks, DMA-linear dest)
#pragma unroll
    for (int t = 0; t < 4; t++) {
        int row = t * 8 + srow;
        int c = sp ^ (row & 7);
        async16(&Qh[(size_t)(q0 + wave * 32 + row) * DK + c * 8],
                &sPw[t * 8 * 64]);
    }

    auto stageK = [&](int k0, int buf) {
#pragma unroll
        for (int t = 0; t < 2; t++) {
            int row = wave * 16 + t * 8 + srow;
            int c = sp ^ (row & 7);
            async16(&Kh[(size_t)(k0 + row) * DK + c * 8],
                    sKb + buf * 4096 + (wave * 16 + t * 8) * 64);
        }
    };
    auto stageV = [&](int k0, int buf) {
#pragma unroll
        for (int t = 0; t < 2; t++) {
            int row = wave * 16 + t * 8 + srow;
            int c = sp ^ (row & 7);
            async16(&Vh[(size_t)row * S_LEN + k0 + c * 8],
                    sVb + buf * 4096 + (wave * 16 + t * 8) * 64);
        }
    };

    stageK(0, 0);
    stageV(0, 0);
    stageK(64, 1);
    __syncthreads();                     // drains all DMA (full vmcnt(0))

    bf16x8 qf[2][2];
#pragma unroll
    for (int nj = 0; nj < 2; nj++)
#pragma unroll
        for (int kk = 0; kk < 2; kk++)
            qf[nj][kk] = ldfrag(&sPw[(nj * 16 + lr) * 64 +
                                     (((kk * 4 + lq) ^ (lr & 7)) * 8)]);

    union { uint4 u; bf16x8 b; } one_u;
    one_u.u = make_uint4(0x3F803F80u, 0x3F803F80u, 0x3F803F80u, 0x3F803F80u);
    const bf16x8 ones = one_u.b;

    f32x4 cacc[2][4] = {};
    f32x4 ssum[2] = {};

    // S^T = K * Q^T : lane holds P[k=mi*16+lq*4+r][q=lr], nj picks q half
    auto qk = [&](const ushort* sk, f32x4 (*sacc)[2]) {
#pragma unroll
        for (int kk = 0; kk < 2; kk++) {
            bf16x8 kf[4];
            int swz = ((kk * 4 + lq) ^ (lr & 7)) * 8;
#pragma unroll
            for (int mi = 0; mi < 4; mi++)
                kf[mi] = ldfrag(&sk[(mi * 16 + lr) * 64 + swz]);
            __builtin_amdgcn_s_setprio(1);
#pragma unroll
            for (int mi = 0; mi < 4; mi++)
#pragma unroll
                for (int nj = 0; nj < 2; nj++)
                    sacc[mi][nj] = __builtin_amdgcn_mfma_f32_16x16x32_bf16(
                        kf[mi], qf[nj][kk], sacc[mi][nj], 0, 0, 0);
            __builtin_amdgcn_s_setprio(0);
        }
    };

    // P = exp2(S^T) -> bf16, write to this wave's P tile [q][k] swizzled
    auto expP = [&](f32x4 (*sacc)[2]) {
#pragma unroll
        for (int mi = 0; mi < 4; mi++)
#pragma unroll
            for (int nj = 0; nj < 2; nj++) {
                float p0 = fast_exp2(sacc[mi][nj][0]);
                float p1 = fast_exp2(sacc[mi][nj][1]);
                float p2 = fast_exp2(sacc[mi][nj][2]);
                float p3 = fast_exp2(sacc[mi][nj][3]);
                uint2 w;
                w.x = packbf_rn(p0, p1);
                w.y = packbf_rn(p2, p3);
                int physc = (mi * 2 + (lq >> 1)) ^ (lr & 7);
                *(uint2*)&sPw[(nj * 16 + lr) * 64 + physc * 8 + (lq & 1) * 4] = w;
            }
    };

    // ctx += P * V^T ; ssum += P * 1
    auto pv = [&](const ushort* sv) {
#pragma unroll
        for (int ks = 0; ks < 2; ks++) {
            bf16x8 pf[2], vf[4];
            int swz = ((ks * 4 + lq) ^ (lr & 7)) * 8;
#pragma unroll
            for (int nj = 0; nj < 2; nj++)
                pf[nj] = ldfrag(&sPw[(nj * 16 + lr) * 64 + swz]);
#pragma unroll
            for (int nd = 0; nd < 4; nd++)
                vf[nd] = ldfrag(&sv[(nd * 16 + lr) * 64 + swz]);
            __builtin_amdgcn_s_setprio(1);
#pragma unroll
            for (int nj = 0; nj < 2; nj++)
#pragma unroll
                for (int nd = 0; nd < 4; nd++)
                    cacc[nj][nd] = __builtin_amdgcn_mfma_f32_16x16x32_bf16(
                        pf[nj], vf[nd], cacc[nj][nd], 0, 0, 0);
#pragma unroll
            for (int nj = 0; nj < 2; nj++)
                ssum[nj] = __builtin_amdgcn_mfma_f32_16x16x32_bf16(
                    pf[nj], ones, ssum[nj], 0, 0, 0);
            __builtin_amdgcn_s_setprio(0);
        }
    };

    {   // prologue: QK(0) + P(0)
        f32x4 s0[4][2] = {};
        qk(sKb, s0);
        expP(s0);
    }
    // protect kb0 from iter-0's stageK(2): all waves' prologue K0 reads have
    // completed before every wave passes this barrier.
    __builtin_amdgcn_s_barrier();

#pragma unroll 2
    for (int k = 0; k < 31; k++) {
        if (k + 2 < 32) stageK((k + 2) * 64, k & 1);
        stageV((k + 1) * 64, (k + 1) & 1);
        f32x4 s2[4][2] = {};
        qk(sKb + ((k + 1) & 1) * 4096, s2);   // QK(k+1): tile landed last iter
        pv(sVb + (k & 1) * 4096);             // PV(k): reads P(k) + V(k)
        pipe_barrier<0>();                    // drain DMA; fence KV buffer reuse
        expP(s2);                             // P(k+1); overlaps next iter's QK
    }
    pv(sVb + 4096);                           // PV(31): tile 31 in vb[31&1]

    const int b = bh >> 4, h = bh & 15;
    float inv[2][4];
#pragma unroll
    for (int nj = 0; nj < 2; nj++)
#pragma unroll
        for (int r = 0; r < 4; r++)
            inv[nj][r] = __builtin_amdgcn_rcpf(ssum[nj][r]);
#pragma unroll
    for (int nj = 0; nj < 2; nj++)
#pragma unroll
        for (int nd = 0; nd < 4; nd++)
#pragma unroll
            for (int r = 0; r < 4; r++) {
                int qrow = q0 + wave * 32 + nj * 16 + lq * 4 + r;
                int d = nd * 16 + lr;
                float v = cacc[nj][nd][r] * inv[nj][r];
                ctx[(size_t)(b * S_LEN + qrow) * D_MODEL + h * DK + d] = f2bf(v);
            }
}

// ---------------- fused mega-kernel (regular launch + spin grid barrier) -------
// All four stages in one dispatch; 3 software grid barriers replace 3 kernel
// boundaries. 768 blocks x 256 thr, 48KB LDS, lb(256,3) -> exactly 3 blocks/CU
// co-resident (spin barrier deadlock-free by construction).
__global__ __launch_bounds__(256, 3) void mega_kernel(
    const float* __restrict__ x,
    const float* __restrict__ Wq, const float* __restrict__ bq,
    const float* __restrict__ Wk, const float* __restrict__ bk,
    const float* __restrict__ Wv, const float* __restrict__ bv,
    const float* __restrict__ Wo, const float* __restrict__ bo,
    char* __restrict__ ws, float* __restrict__ outF) {
    __shared__ __align__(16) ushort smem[24576];   // 48 KB, reused per phase

    ushort* xb    = (ushort*)(ws);                        // 8 MB
    ushort* wqkv  = (ushort*)(ws + (8ull  << 20));        // 6 MB (B^T)
    ushort* wo_t  = (ushort*)(ws + (14ull << 20));        // 2 MB (B^T)
    ushort* qbuf  = (ushort*)(ws + (16ull << 20));        // 8 MB [32][2048][64]
    ushort* kbuf  = (ushort*)(ws + (24ull << 20));        // 8 MB [32][2048][64]
    ushort* vtb   = (ushort*)(ws + (32ull << 20));        // 8 MB [32][64][2048]
    ushort* ctxb  = (ushort*)(ws + (40ull << 20));        // 8 MB [4096][1024]
    float*  biasq = (float*)(ws + (48ull << 20));         // 12 KB [3072]
    uint32_t* bar = (uint32_t*)(ws + (49ull << 20));      // 4 B (memset to 0)

    const int tid = threadIdx.x;

    // ---- phase A: converts -------------------------------------------------
    for (int wb = blockIdx.x; wb < 8204; wb += 768) {
        if (wb < 4096) {                 // x f32 -> bf16
            int i = wb * 256 + tid;
            float4 v = ((const float4*)x)[i];
            ushort4 o;
            o.x = f2bf(v.x); o.y = f2bf(v.y); o.z = f2bf(v.z); o.w = f2bf(v.w);
            ((ushort4*)xb)[i] = o;
        } else if (wb < 8192) {          // 4 weight transposes (f32 -> bf16 B^T)
            float (*tile)[33] = (float(*)[33])(void*)smem;
            int t = wb - 4096;
            int z = t >> 10, rem = t & 1023;
            const float* W; ushort* D;
            switch (z) {
                case 0: W = Wq; D = wqkv; break;
                case 1: W = Wk; D = wqkv + 1024 * 1024; break;
                case 2: W = Wv; D = wqkv + 2 * 1024 * 1024; break;
                default: W = Wo; D = wo_t; break;
            }
            int by = (rem >> 5) * 32, bx = (rem & 31) * 32;
            int tx = tid & 31, ty = tid >> 5;            // 32 x 8
#pragma unroll
            for (int j = 0; j < 32; j += 8)
                tile[ty + j][tx] = W[(size_t)(by + ty + j) * D_MODEL + bx + tx];
            __syncthreads();
#pragma unroll
            for (int j = 0; j < 32; j += 8)
                D[(size_t)(bx + ty + j) * D_MODEL + by + tx] =
                    f2bf(tile[tx][ty + j]);
            __syncthreads();             // tile reads done before next overwrite
        } else {                         // bias pack
            int i = (wb - 8192) * 256 + tid;             // 0..3071
            float v = (i < 1024) ? bq[i]
                                 : (i < 2048 ? bk[i - 1024] : bv[i - 2048]);
            biasq[i] = v;
        }
    }
    grid_bar(bar);

    // ---- phase B: QKV projections -----------------------------------------
    gemm_body<0>(blockIdx.x, smem, xb, wqkv, biasq,
                 qbuf, kbuf, vtb, nullptr, nullptr);
    grid_bar(bar);

    // ---- phase C: flash attention -----------------------------------------
    if (blockIdx.x < 512)
        attn_body(blockIdx.x, smem, qbuf, kbuf, vtb, ctxb);
    grid_bar(bar);

    // ---- phase D: output projection + residual ----------------------------
    if (blockIdx.x < 512)
        gemm_body<1>(blockIdx.x, smem, ctxb, wo_t, bo,
                     nullptr, nullptr, nullptr, x, outF);
}

// ---------------- launch ----------------

extern "C" void kernel_launch(void* const* d_in, const int* in_sizes, int n_in,
                              void* d_out, int out_size, void* d_ws, size_t ws_size,
                              hipStream_t stream) {
    const float* x  = (const float*)d_in[0];
    const float* Wq = (const float*)d_in[1];
    const float* bq = (const float*)d_in[2];
    const float* Wk = (const float*)d_in[3];
    const float* bk = (const float*)d_in[4];
    const float* Wv = (const float*)d_in[5];
    const float* bv = (const float*)d_in[6];
    const float* Wo = (const float*)d_in[7];
    const float* bo = (const float*)d_in[8];
    char* ws = (char*)d_ws;
    float* outF = (float*)d_out;

    // reset the grid-barrier counter (graph-capturable; replayed per rep)
    hipMemsetAsync(ws + (49ull << 20), 0, 4, stream);

    mega_kernel<<<768, 256, 0, stream>>>(
        x, Wq, bq, Wk, bk, Wv, bv, Wo, bo, ws, outF);
}

// Round 13
// 185.899 us; speedup vs baseline: 3.2811x; 3.2811x over previous
//
#include <hip/hip_runtime.h>
#include <hip/hip_bf16.h>
#include <stdint.h>

#define D_MODEL 1024
#define NH 16
#define DK 64
#define S_LEN 2048

typedef __attribute__((ext_vector_type(8))) __bf16 bf16x8;
typedef __attribute__((ext_vector_type(4))) float f32x4;

#define GLOBAL_AS __attribute__((address_space(1)))
#define LDS_AS    __attribute__((address_space(3)))

// async global->LDS DMA, 16B per lane; lane i's 16B lands at ldsbase + i*16.
__device__ __forceinline__ void async16(const ushort* g, ushort* l) {
    __builtin_amdgcn_global_load_lds(
        (const GLOBAL_AS uint32_t*)(uintptr_t)(const void*)g,
        (LDS_AS uint32_t*)(uint32_t)(uintptr_t)(void*)l,
        16, 0, 0);
}

// raw barrier with fine-grained vmcnt: waits until <=N VMEM ops outstanding.
template <int N>
__device__ __forceinline__ void pipe_barrier() {
    asm volatile("s_waitcnt vmcnt(%0)\n\ts_barrier" :: "n"(N) : "memory");
}

__device__ __forceinline__ float fast_exp2(float x) {
    float r;
    asm("v_exp_f32 %0, %1" : "=v"(r) : "v"(x));   // D = 2^S0
    return r;
}

// fp32 -> bf16 (RNE)
__device__ __forceinline__ ushort f2bf(float f) {
    union { float f; uint32_t u; } v; v.f = f;
    uint32_t lsb = (v.u >> 16) & 1u;
    return (ushort)((v.u + 0x7fffu + lsb) >> 16);
}

// two fp32 -> packed bf16x2 (round-half-up)
__device__ __forceinline__ uint32_t packbf(float a, float b) {
    union { float f; uint32_t u; } x, y; x.f = a; y.f = b;
    return ((x.u + 0x8000u) >> 16) | ((y.u + 0x8000u) & 0xffff0000u);
}

// two fp32 -> packed bf16x2 via native v_cvt_pk_bf16_f32 (RNE, 1 instr)
__device__ __forceinline__ uint32_t packbf_rn(float a, float b) {
    union { __hip_bfloat162 h; uint32_t u; } cv;
    cv.h = __float22bfloat162_rn(make_float2(a, b));
    return cv.u;
}

__device__ __forceinline__ bf16x8 ldfrag(const ushort* p) {
    union { uint4 u; bf16x8 b; } cv;
    cv.u = *(const uint4*)p;
    return cv.b;
}

// ---------------- fused convert kernel ----------------------------------------
// blocks [0,4096): x f32 -> bf16.  [4096,8192): 4 weight transposes (f32->bf16
// B^T).  [8192,8204): bias pack.  Parts are independent; branch is block-uniform.
__global__ void cvt_fused_kernel(
    const float* __restrict__ x, ushort* __restrict__ xb,
    const float* __restrict__ W0, const float* __restrict__ W1,
    const float* __restrict__ W2, const float* __restrict__ W3,
    ushort* __restrict__ D0, ushort* __restrict__ D1,
    ushort* __restrict__ D2, ushort* __restrict__ D3,
    const float* __restrict__ bq, const float* __restrict__ bk,
    const float* __restrict__ bv, float* __restrict__ biasq) {
    __shared__ float tile[32][33];
    const int bid = blockIdx.x, tid = threadIdx.x;
    if (bid < 4096) {
        int i = bid * 256 + tid;
        float4 v = ((const float4*)x)[i];
        ushort4 o;
        o.x = f2bf(v.x); o.y = f2bf(v.y); o.z = f2bf(v.z); o.w = f2bf(v.w);
        ((ushort4*)xb)[i] = o;
    } else if (bid < 8192) {
        int t = bid - 4096;
        int z = t >> 10, rem = t & 1023;
        const float* W; ushort* D;
        switch (z) {
            case 0: W = W0; D = D0; break;
            case 1: W = W1; D = D1; break;
            case 2: W = W2; D = D2; break;
            default: W = W3; D = D3; break;
        }
        int by = (rem >> 5) * 32, bx = (rem & 31) * 32;
        int tx = tid & 31, ty = tid >> 5;            // 32 x 8
#pragma unroll
        for (int j = 0; j < 32; j += 8)
            tile[ty + j][tx] = W[(size_t)(by + ty + j) * D_MODEL + bx + tx];
        __syncthreads();
#pragma unroll
        for (int j = 0; j < 32; j += 8)
            D[(size_t)(bx + ty + j) * D_MODEL + by + tx] = f2bf(tile[tx][ty + j]);
    } else {
        int i = (bid - 8192) * 256 + tid;            // 0..3071
        float v = (i < 1024) ? bq[i] : (i < 2048 ? bk[i - 1024] : bv[i - 2048]);
        biasq[i] = v;
    }
}

// ---------------- MFMA GEMM ---------------------------------------------------
// BK=32, THREE buffers (48/36 KB) -> 3 blocks/CU residency, single-generation
// grid. Stage issued at loop top; awaited stage is ~2 iterations old, covering
// HBM latency. Full unroll makes the %3 buffer rotation static.
// MODE 0: tile 128x128, grid 768, N-striped XCD. Each block is wholly Q, K or V.
// MODE 1: tile 128x64, grid 512, M-striped XCD; out = acc + bias + residual.
template <int MODE>
__global__ __launch_bounds__(256, 3) void gemm_kernel(
    const ushort* __restrict__ A, const ushort* __restrict__ Bt,
    const float* __restrict__ bias,
    ushort* __restrict__ outQ, ushort* __restrict__ outK, ushort* __restrict__ outVt,
    const float* __restrict__ xres, float* __restrict__ outF) {
    constexpr int BN = (MODE == 0) ? 128 : 64;
    constexpr int NI = (MODE == 0) ? 4 : 2;
    constexpr int NS = (MODE == 0) ? 4 : 3;        // per-wave DMA instrs / stage
    constexpr int ABUF = 4096;                     // ushorts per A buffer
    constexpr int BBUF = (MODE == 0) ? 4096 : 2048;
    constexpr int SMEM = (MODE == 0) ? 24576 : 18432;  // 48 / 36 KB
    __shared__ __align__(16) ushort smem[SMEM];
    ushort* sAb = smem;
    ushort* sBb = smem + 3 * ABUF;

    const int tid = threadIdx.x;
    const int wave = tid >> 6, lane = tid & 63;
    const int lr = lane & 15, lq = lane >> 4;
    const int srow = lane >> 3, sp = lane & 7;     // staging: 8 lanes / 128B row

    const int bid = blockIdx.x;
    const int xcd = bid & 7, lb = bid >> 3;
    int bx, by;
    if (MODE == 0) { bx = xcd * 3 + (lb % 3); by = lb / 3; }       // N-stripe
    else           { by = xcd * 4 + (lb & 3); bx = lb >> 2; }      // M-stripe
    const int blockM = by * 128;
    const int blockN = bx * BN;
    const int waveM = (wave >> 1) * 64;
    const int waveN = (MODE == 0) ? (wave & 1) * 64 : (wave & 1) * 32;

    // stage one BK=32 tile pair into buffer `buf`
    auto stage = [&](int k0, int buf) {
        ushort* a = sAb + buf * ABUF;
#pragma unroll
        for (int t = 0; t < 2; t++) {
            int Rb = wave * 16 + t * 8;            // uniform LDS row base
            int R = Rb + srow;
            int L = sp ^ (R & 7);
            int m = 2 * R + (L >> 2);
            int kc = L & 3;
            async16(&A[(size_t)(blockM + m) * D_MODEL + k0 + kc * 8], a + Rb * 64);
        }
        ushort* b = sBb + buf * BBUF;
        if (MODE == 0) {
#pragma unroll
            for (int t = 0; t < 2; t++) {
                int Rb = wave * 16 + t * 8;
                int R = Rb + srow;
                int L = sp ^ (R & 7);
                int n = 2 * R + (L >> 2);
                int kc = L & 3;
                async16(&Bt[(size_t)(blockN + n) * D_MODEL + k0 + kc * 8], b + Rb * 64);
            }
        } else {
            int Rb = wave * 8;
            int R = Rb + srow;
            int L = sp ^ (R & 7);
            int n = 2 * R + (L >> 2);
            int kc = L & 3;
            async16(&Bt[(size_t)(blockN + n) * D_MODEL + k0 + kc * 8], b + Rb * 64);
        }
    };

    // fragment read offsets (row-xor invariant across mi since rows step by 8)
    const int RA = (waveM >> 1) + (lr >> 1);
    const int offA = RA * 64 + ((((lr & 1) * 4 + lq) ^ (RA & 7)) * 8);
    const int RB = (waveN >> 1) + (lr >> 1);
    const int offB = RB * 64 + ((((lr & 1) * 4 + lq) ^ (RB & 7)) * 8);

    f32x4 acc[4][NI] = {};

    stage(0, 0);
    stage(32, 1);
    pipe_barrier<NS>();   // buf0 landed; buf1 in flight

#pragma unroll
    for (int k = 0; k < 32; k++) {
        const int buf = k % 3;
        if (k + 2 < 32) stage((k + 2) * 32, (k + 2) % 3);
        const ushort* a = sAb + buf * ABUF;
        const ushort* b = sBb + buf * BBUF;
        bf16x8 af[4], bfr[NI];
#pragma unroll
        for (int mi = 0; mi < 4; mi++)
            af[mi] = ldfrag(&a[offA + mi * 512]);
#pragma unroll
        for (int ni = 0; ni < NI; ni++)
            bfr[ni] = ldfrag(&b[offB + ni * 512]);
#pragma unroll
        for (int mi = 0; mi < 4; mi++)
#pragma unroll
            for (int ni = 0; ni < NI; ni++)
                acc[mi][ni] = __builtin_amdgcn_mfma_f32_16x16x32_bf16(
                    af[mi], bfr[ni], acc[mi][ni], 0, 0, 0);
        if (k < 30) pipe_barrier<NS>();           // awaited stage is ~2 iters old
        else if (k == 30) pipe_barrier<0>();
    }
    __syncthreads();   // all K-loop LDS reads done; smem now reused for epilogue

    const int bglob = blockM >> 11;
    const int sbase = blockM & 2047;

    if (MODE == 0) {
        const int which = bx >> 3;                // 0=Q 1=K 2=V, uniform per block
        if (which < 2) {
            // C -> LDS [m][n], stride 136, then coalesced [bh][s][d] stores
            const float scale = (which == 0) ? 0.1803368801f : 1.0f;  // 1/8*log2e
#pragma unroll
            for (int ni = 0; ni < 4; ni++) {
                const int n_loc = waveN + ni * 16 + lr;
                const float bn = bias[blockN + n_loc];
#pragma unroll
                for (int mi = 0; mi < 4; mi++)
#pragma unroll
                    for (int r = 0; r < 4; r++) {
                        int m_loc = waveM + mi * 16 + lq * 4 + r;
                        smem[m_loc * 136 + n_loc] =
                            f2bf((acc[mi][ni][r] + bn) * scale);
                    }
            }
            __syncthreads();
            ushort* outp = (which == 0) ? outQ : outK;
            const int hbase = (which == 0) ? bx * 2 : (bx - 8) * 2;
#pragma unroll
            for (int j = 0; j < 8; j++) {
                int c = tid + j * 256;            // 2048 chunks of 16B
                int m = c >> 4, nc = c & 15;
                int hh = nc >> 3, d8 = nc & 7;
                uint4 w = *(uint4*)&smem[m * 136 + nc * 8];
                size_t bh = (size_t)(bglob * NH + hbase + hh);
                *(uint4*)&outp[(bh * S_LEN + sbase + m) * DK + d8 * 8] = w;
            }
        } else {
            // V: C -> LDS [n][m] (b64 packed writes), then [bh][d][s] stores
#pragma unroll
            for (int ni = 0; ni < 4; ni++) {
                const int n_loc = waveN + ni * 16 + lr;
                const float bn = bias[blockN + n_loc];
#pragma unroll
                for (int mi = 0; mi < 4; mi++) {
                    uint2 w;
                    w.x = packbf(acc[mi][ni][0] + bn, acc[mi][ni][1] + bn);
                    w.y = packbf(acc[mi][ni][2] + bn, acc[mi][ni][3] + bn);
                    int m_base = waveM + mi * 16 + lq * 4;
                    *(uint2*)&smem[n_loc * 136 + m_base] = w;
                }
            }
            __syncthreads();
            const int hbase = (bx - 16) * 2;
#pragma unroll
            for (int j = 0; j < 8; j++) {
                int c = tid + j * 256;
                int n_loc = c >> 4, m8 = c & 15;
                int d = n_loc & 63, hh = n_loc >> 6;
                uint4 w = *(uint4*)&smem[n_loc * 136 + m8 * 8];
                size_t bh = (size_t)(bglob * NH + hbase + hh);
                *(uint4*)&outVt[(bh * DK + d) * S_LEN + sbase + m8 * 8] = w;
            }
        }
    } else {
        // fp32 out: C+bias -> LDS [m][n] stride 68, then +residual float4 stores
        float* sCf = (float*)smem;
#pragma unroll
        for (int ni = 0; ni < 2; ni++) {
            const int n_loc = waveN + ni * 16 + lr;
            const float bn = bias[blockN + n_loc];
#pragma unroll
            for (int mi = 0; mi < 4; mi++)
#pragma unroll
                for (int r = 0; r < 4; r++) {
                    int m_loc = waveM + mi * 16 + lq * 4 + r;
                    sCf[m_loc * 68 + n_loc] = acc[mi][ni][r] + bn;
                }
        }
        __syncthreads();
#pragma unroll
        for (int j = 0; j < 8; j++) {
            int c = tid + j * 256;               // 2048 chunks of 16B
            int m = c >> 4, nc = c & 15;
            float4 v = *(float4*)&sCf[m * 68 + nc * 4];
            size_t idx = (size_t)(blockM + m) * D_MODEL + blockN + nc * 4;
            float4 xr = *(const float4*)&xres[idx];
            v.x += xr.x; v.y += xr.y; v.z += xr.z; v.w += xr.w;
            *(float4*)&outF[idx] = v;
        }
    }
}

// ---------------- flash attention --------------------------------------------
// Best-measured configuration (46.0-46.2us x5 dispatches): 512 blocks x
// 4 waves x 32 q-rows, K and V triple-buffered, K staged at distance 3,
// V at distance 2, per-iter barrier waits vmcnt(4) -- exactly this
// iteration's 4 DMA ops stay in flight across the barrier (T4 counted-vmcnt).
// Needed-by proof: at barrier k, draining to 4 completes iter k-1's stages =
// K(k+2) (read by qk at iter k+1) and V(k+1) (read by pv at iter k+1).
// Tail: <2> at k=29 (drains V(30)), <0> at k=30 (drains V(31)).
// LDS: 3x8(K) + 3x8(V) + 16(QP) = 64KB.
__global__ __launch_bounds__(256, 2) void attn_kernel(
    const ushort* __restrict__ Q, const ushort* __restrict__ Km,
    const ushort* __restrict__ Vt, ushort* __restrict__ ctx) {
    const int bid = blockIdx.x;
    const int xcd = bid & 7, lb = bid >> 3;
    const int bh = xcd * 4 + (lb & 3);
    const int qt = lb >> 2;
    const int q0 = qt * 128;
    __shared__ __align__(16) ushort sK[3][64 * 64];   // 24 KB
    __shared__ __align__(16) ushort sV[3][64 * 64];   // 24 KB
    __shared__ __align__(16) ushort sQP[4][32 * 64];  // 16 KB (Q, then P)
    const int tid = threadIdx.x;
    const int wave = tid >> 6, lane = tid & 63;
    const int lr = lane & 15, lq = lane >> 4;
    const int srow = lane >> 3, sp = lane & 7;
    const ushort* Qh = Q + (size_t)bh * S_LEN * DK;
    const ushort* Kh = Km + (size_t)bh * S_LEN * DK;
    const ushort* Vh = Vt + (size_t)bh * DK * S_LEN;
    ushort* sPw = sQP[wave];

    // stage this wave's 32 Q rows (swizzled chunks, DMA-linear dest)
#pragma unroll
    for (int t = 0; t < 4; t++) {
        int row = t * 8 + srow;
        int c = sp ^ (row & 7);
        async16(&Qh[(size_t)(q0 + wave * 32 + row) * DK + c * 8],
                &sPw[t * 8 * 64]);
    }

    auto stageK = [&](int k0, int buf) {
#pragma unroll
        for (int t = 0; t < 2; t++) {
            int row = wave * 16 + t * 8 + srow;
            int c = sp ^ (row & 7);
            async16(&Kh[(size_t)(k0 + row) * DK + c * 8],
                    &sK[buf][(wave * 16 + t * 8) * 64]);
        }
    };
    auto stageV = [&](int k0, int buf) {
#pragma unroll
        for (int t = 0; t < 2; t++) {
            int row = wave * 16 + t * 8 + srow;
            int c = sp ^ (row & 7);
            async16(&Vh[(size_t)row * S_LEN + k0 + c * 8],
                    &sV[buf][(wave * 16 + t * 8) * 64]);
        }
    };

    // prologue stages: K(0..2), V(0..1)
    stageK(0, 0);
    stageV(0, 0);
    stageK(64, 1);
    stageV(64, 1);
    stageK(128, 2);
    __syncthreads();                     // drains all DMA (full vmcnt(0))

    bf16x8 qf[2][2];
#pragma unroll
    for (int nj = 0; nj < 2; nj++)
#pragma unroll
        for (int kk = 0; kk < 2; kk++)
            qf[nj][kk] = ldfrag(&sPw[(nj * 16 + lr) * 64 +
                                     (((kk * 4 + lq) ^ (lr & 7)) * 8)]);

    union { uint4 u; bf16x8 b; } one_u;
    one_u.u = make_uint4(0x3F803F80u, 0x3F803F80u, 0x3F803F80u, 0x3F803F80u);
    const bf16x8 ones = one_u.b;

    f32x4 cacc[2][4] = {};
    f32x4 ssum[2] = {};

    // S^T = K * Q^T : lane holds P[k=mi*16+lq*4+r][q=lr], nj picks q half
    auto qk = [&](const ushort* sk, f32x4 (*sacc)[2]) {
#pragma unroll
        for (int kk = 0; kk < 2; kk++) {
            bf16x8 kf[4];
            int swz = ((kk * 4 + lq) ^ (lr & 7)) * 8;
#pragma unroll
            for (int mi = 0; mi < 4; mi++)
                kf[mi] = ldfrag(&sk[(mi * 16 + lr) * 64 + swz]);
            __builtin_amdgcn_s_setprio(1);
#pragma unroll
            for (int mi = 0; mi < 4; mi++)
#pragma unroll
                for (int nj = 0; nj < 2; nj++)
                    sacc[mi][nj] = __builtin_amdgcn_mfma_f32_16x16x32_bf16(
                        kf[mi], qf[nj][kk], sacc[mi][nj], 0, 0, 0);
            __builtin_amdgcn_s_setprio(0);
        }
    };

    // P = exp2(S^T) -> bf16, write to this wave's P tile [q][k] swizzled
    auto expP = [&](f32x4 (*sacc)[2]) {
#pragma unroll
        for (int mi = 0; mi < 4; mi++)
#pragma unroll
            for (int nj = 0; nj < 2; nj++) {
                float p0 = fast_exp2(sacc[mi][nj][0]);
                float p1 = fast_exp2(sacc[mi][nj][1]);
                float p2 = fast_exp2(sacc[mi][nj][2]);
                float p3 = fast_exp2(sacc[mi][nj][3]);
                uint2 w;
                w.x = packbf_rn(p0, p1);
                w.y = packbf_rn(p2, p3);
                int physc = (mi * 2 + (lq >> 1)) ^ (lr & 7);
                *(uint2*)&sPw[(nj * 16 + lr) * 64 + physc * 8 + (lq & 1) * 4] = w;
            }
    };

    // ctx += P * V^T ; ssum += P * 1
    auto pv = [&](const ushort* sv) {
#pragma unroll
        for (int ks = 0; ks < 2; ks++) {
            bf16x8 pf[2], vf[4];
            int swz = ((ks * 4 + lq) ^ (lr & 7)) * 8;
#pragma unroll
            for (int nj = 0; nj < 2; nj++)
                pf[nj] = ldfrag(&sPw[(nj * 16 + lr) * 64 + swz]);
#pragma unroll
            for (int nd = 0; nd < 4; nd++)
                vf[nd] = ldfrag(&sv[(nd * 16 + lr) * 64 + swz]);
            __builtin_amdgcn_s_setprio(1);
#pragma unroll
            for (int nj = 0; nj < 2; nj++)
#pragma unroll
                for (int nd = 0; nd < 4; nd++)
                    cacc[nj][nd] = __builtin_amdgcn_mfma_f32_16x16x32_bf16(
                        pf[nj], vf[nd], cacc[nj][nd], 0, 0, 0);
#pragma unroll
            for (int nj = 0; nj < 2; nj++)
                ssum[nj] = __builtin_amdgcn_mfma_f32_16x16x32_bf16(
                    pf[nj], ones, ssum[nj], 0, 0, 0);
            __builtin_amdgcn_s_setprio(0);
        }
    };

    {   // prologue: QK(0) + P(0)
        f32x4 s0[4][2] = {};
        qk(sK[0], s0);
        expP(s0);
    }
    // protect kb0 from iter-0's stageK(3) (3%3=0): all waves' prologue K0
    // reads are register-complete before each wave reaches this barrier.
    __builtin_amdgcn_s_barrier();

#pragma unroll 3
    for (int k = 0; k < 31; k++) {
        if (k + 3 < 32) stageK((k + 3) * 64, (k + 3) % 3);
        if (k + 2 < 32) stageV((k + 2) * 64, (k + 2) % 3);
        f32x4 s2[4][2] = {};
        qk(sK[(k + 1) % 3], s2);         // QK(k+1): staged 2 iters ago
        pv(sV[k % 3]);                   // PV(k): P(k) + V(k)
        if (k < 29) pipe_barrier<4>();   // this iter's 4 DMA stay in flight
        else if (k == 29) pipe_barrier<2>();
        else pipe_barrier<0>();
        expP(s2);                        // P(k+1); overlaps next iter's QK
    }
    pv(sV[31 % 3]);                      // PV(31)

    const int b = bh >> 4, h = bh & 15;
    float inv[2][4];
#pragma unroll
    for (int nj = 0; nj < 2; nj++)
#pragma unroll
        for (int r = 0; r < 4; r++)
            inv[nj][r] = __builtin_amdgcn_rcpf(ssum[nj][r]);
#pragma unroll
    for (int nj = 0; nj < 2; nj++)
#pragma unroll
        for (int nd = 0; nd < 4; nd++)
#pragma unroll
            for (int r = 0; r < 4; r++) {
                int qrow = q0 + wave * 32 + nj * 16 + lq * 4 + r;
                int d = nd * 16 + lr;
                float v = cacc[nj][nd][r] * inv[nj][r];
                ctx[(size_t)(b * S_LEN + qrow) * D_MODEL + h * DK + d] = f2bf(v);
            }
}

// ---------------- launch ----------------

extern "C" void kernel_launch(void* const* d_in, const int* in_sizes, int n_in,
                              void* d_out, int out_size, void* d_ws, size_t ws_size,
                              hipStream_t stream) {
    const float* x  = (const float*)d_in[0];
    const float* Wq = (const float*)d_in[1];
    const float* bq = (const float*)d_in[2];
    const float* Wk = (const float*)d_in[3];
    const float* bk = (const float*)d_in[4];
    const float* Wv = (const float*)d_in[5];
    const float* bv = (const float*)d_in[6];
    const float* Wo = (const float*)d_in[7];
    const float* bo = (const float*)d_in[8];

    char* ws = (char*)d_ws;
    ushort* xb    = (ushort*)(ws);                        // 8 MB
    ushort* wqkv  = (ushort*)(ws + (8ull  << 20));        // 6 MB (B^T)
    ushort* wo_t  = (ushort*)(ws + (14ull << 20));        // 2 MB (B^T)
    ushort* qbuf  = (ushort*)(ws + (16ull << 20));        // 8 MB [32][2048][64]
    ushort* kbuf  = (ushort*)(ws + (24ull << 20));        // 8 MB [32][2048][64]
    ushort* vtb   = (ushort*)(ws + (32ull << 20));        // 8 MB [32][64][2048]
    ushort* ctx   = (ushort*)(ws + (40ull << 20));        // 8 MB [4096][1024]
    float*  biasq = (float*)(ws + (48ull << 20));         // 12 KB [3072]

    cvt_fused_kernel<<<8204, 256, 0, stream>>>(
        x, xb, Wq, Wk, Wv, Wo,
        wqkv, wqkv + 1024 * 1024, wqkv + 2 * 1024 * 1024, wo_t,
        bq, bk, bv, biasq);

    gemm_kernel<0><<<768, 256, 0, stream>>>(
        xb, wqkv, biasq, qbuf, kbuf, vtb, nullptr, nullptr);
    attn_kernel<<<512, 256, 0, stream>>>(qbuf, kbuf, vtb, ctx);
    gemm_kernel<1><<<512, 256, 0, stream>>>(
        ctx, wo_t, bo, nullptr, nullptr, nullptr, x, (float*)d_out);
}